// Round 19
// baseline (144.812 us; speedup 1.0000x reference)
//
#include <hip/hip_runtime.h>
#include <hip/hip_bf16.h>

typedef __attribute__((ext_vector_type(8)))  short    s16x8;
typedef __attribute__((ext_vector_type(4)))  short    s16x4;
typedef __attribute__((ext_vector_type(8)))  __bf16   bf16x8;
typedef __attribute__((ext_vector_type(4)))  float    f32x4;
typedef __attribute__((ext_vector_type(16))) float    f32x16;
typedef __attribute__((ext_vector_type(4)))  unsigned u32x4;

__device__ __forceinline__ short f2bf(float f) {
  unsigned u = __builtin_bit_cast(unsigned, f);
  u += 0x7fffu + ((u >> 16) & 1u);          // round-to-nearest-even
  return (short)(u >> 16);
}

// two f32 -> packed bf16 pair via hardware packed cvt (m240). memcpy because
// __hip_bfloat162 is not trivially copyable (bit_cast rejected, r13).
__device__ __forceinline__ unsigned cvt2bf(float a, float b) {
  __hip_bfloat162 r = __float22bfloat162_rn(make_float2(a, b));
  unsigned u;
  __builtin_memcpy(&u, &r, 4);
  return u;
}

__device__ __forceinline__ f32x4 mfma16(s16x8 a, s16x8 b, f32x4 c) {
  return __builtin_amdgcn_mfma_f32_16x16x32_bf16(
      __builtin_bit_cast(bf16x8, a), __builtin_bit_cast(bf16x8, b), c, 0, 0, 0);
}

__device__ __forceinline__ f32x16 mfma32(s16x8 a, s16x8 b, f32x16 c) {
  return __builtin_amdgcn_mfma_f32_32x32x16_bf16(
      __builtin_bit_cast(bf16x8, a), __builtin_bit_cast(bf16x8, b), c, 0, 0, 0);
}

__device__ __forceinline__ void glds16(const short* g, short* l) {
  __builtin_amdgcn_global_load_lds(
      (__attribute__((address_space(1))) const void*)g,
      (__attribute__((address_space(3))) void*)l, 16, 0, 0);
}

// ---------------- merged transpose + cast of the 3 weights ----------------
__global__ __launch_bounds__(256) void transpose_cast_all(
    const float* __restrict__ s0, short* __restrict__ d0,
    const float* __restrict__ s1, short* __restrict__ d1,
    const float* __restrict__ s2, short* __restrict__ d2) {
  __shared__ float t[32 * 33];
  int id = blockIdx.x;
  const float* src; short* dst; int R, C, bx, by;
  if (id < 288)      { src = s0; dst = d0; R = 768; C = 384;  bx = id % 12;           by = id / 12; }
  else if (id < 720) { int l = id - 288; src = s1; dst = d1; R = 384; C = 1152; bx = l % 36; by = l / 36; }
  else               { int l = id - 720; src = s2; dst = d2; R = 384; C = 768;  bx = l % 24; by = l / 24; }
  int tid = threadIdx.x;
  int c0 = bx * 32, r0 = by * 32;
  for (int rep = 0; rep < 4; ++rep) {
    int idx = rep * 256 + tid;
    int rr = idx >> 5, cc = idx & 31;
    t[rr * 33 + cc] = src[(size_t)(r0 + rr) * C + c0 + cc];
  }
  __syncthreads();
  for (int rep = 0; rep < 4; ++rep) {
    int idx = rep * 256 + tid;
    int cc = idx >> 5, rr = idx & 31;
    dst[(size_t)(c0 + cc) * R + r0 + rr] = f2bf(t[rr * 33 + cc]);
  }
}

// ---------------- m97-style bf16 GEMM, templated block-M ----------------
// MODE 0: bf16 out. MODE 1: f32 out. MODE 2: qkv scatter (q pre-scaled),
//   V written DIRECTLY to vt[bhs][d][1024] (transposed) as s16x4 quads.
// AF32: A is f32; reg-stage (issue early, convert+ds_write after MFMA).
template <int MODE, bool AF32, int BM>
__global__ __launch_bounds__(256, 2) void gemm_bf16(
    const short* __restrict__ A, const float* __restrict__ Af,
    const short* __restrict__ Bt,
    const float* __restrict__ bias, void* __restrict__ out,
    short* __restrict__ q_p, short* __restrict__ k_p, short* __restrict__ vt,
    int M, int N, int K) {
  constexpr int WM  = BM / 2;    // wave M-extent
  constexpr int MI  = WM / 16;   // M fragments per wave
  constexpr int AIT = BM / 32;   // A-stage iterations (256 thr x 16B)
  __shared__ short lds[2][(BM + 128) * 64];
  int tid = threadIdx.x;
  int lane = tid & 63, wid = tid >> 6;
  int l15 = lane & 15, g = lane >> 4;
  int nbn = N >> 7;
  int nwg = gridDim.x;
  int bid = blockIdx.x;
  int chunk = nwg >> 3;                       // all grids are %8 == 0
  int swz_bid = (bid & 7) * chunk + (bid >> 3);
  int bm = swz_bid / nbn, bn = swz_bid % nbn;
  int wr = wid >> 1, wc = wid & 1;

  const short* Ab = AF32 ? nullptr : (A + (size_t)(bm * BM) * K);
  const float* Afb = AF32 ? (Af + (size_t)(bm * BM) * K) : nullptr;
  const short* Bb = Bt + (size_t)(bn * 128) * K;

  f32x4 acc[MI][4];
#pragma unroll
  for (int i = 0; i < MI; ++i)
#pragma unroll
    for (int j = 0; j < 4; ++j) acc[i][j] = (f32x4){0.f, 0.f, 0.f, 0.f};

  f32x4 areg[AIT][2];                         // AF32: 8 floats per c-slot
  int nk = K >> 6;

  auto stageB = [&](int bufi, int kt) {
    const short* gb = Bb + kt * 64;
#pragma unroll
    for (int it = 0; it < 4; ++it) {
      int c = it * 256 + tid;
      int row = c >> 3, pc = c & 7;
      int lc = pc ^ (row & 7);                // pre-swizzled source (rule #21)
      glds16(gb + (size_t)row * K + lc * 8,
             &lds[bufi][BM * 64 + (it * 256 + wid * 64) * 8]);
    }
  };
  auto stageA_lds = [&](int bufi, int kt) {
    const short* ga = Ab + kt * 64;
#pragma unroll
    for (int it = 0; it < AIT; ++it) {
      int c = it * 256 + tid;
      int row = c >> 3, pc = c & 7;
      int lc = pc ^ (row & 7);
      glds16(ga + (size_t)row * K + lc * 8,
             &lds[bufi][(it * 256 + wid * 64) * 8]);
    }
  };
  auto stageA_issue = [&](int kt) {           // f32 global -> regs (no wait yet)
#pragma unroll
    for (int it = 0; it < AIT; ++it) {
      int c = it * 256 + tid;
      int row = c >> 3, pc = c & 7;
      int lc = pc ^ (row & 7);
      const float* src = Afb + (size_t)row * K + kt * 64 + lc * 8;
      areg[it][0] = *(const f32x4*)(src);
      areg[it][1] = *(const f32x4*)(src + 4);
    }
  };
  auto stageA_write = [&](int bufi) {         // regs -> bf16 -> LDS (same image)
#pragma unroll
    for (int it = 0; it < AIT; ++it) {
      int c = it * 256 + tid;
      s16x8 o;
#pragma unroll
      for (int q = 0; q < 4; ++q) {
        o[q]     = f2bf(areg[it][0][q]);
        o[q + 4] = f2bf(areg[it][1][q]);
      }
      *(s16x8*)(&lds[bufi][0] + (size_t)c * 8) = o;
    }
  };

  if (AF32) { stageA_issue(0); stageB(0, 0); stageA_write(0); }
  else      { stageA_lds(0, 0); stageB(0, 0); }
  __syncthreads();
  int buf = 0;
  for (int kt = 0; kt < nk; ++kt) {
    bool more = (kt + 1 < nk);
    if (more) {
      if (AF32) stageA_issue(kt + 1); else stageA_lds(buf ^ 1, kt + 1);
      stageB(buf ^ 1, kt + 1);
    }
    const short* la = &lds[buf][0];
    const short* lb = &lds[buf][BM * 64];
    s16x8 af[MI][2], bfv[4][2];
#pragma unroll
    for (int i = 0; i < MI; ++i)
#pragma unroll
      for (int kk = 0; kk < 2; ++kk) {
        int row = wr * WM + i * 16 + l15;
        int ch = (kk * 4 + g) ^ (l15 & 7);
        af[i][kk] = *(const s16x8*)(la + row * 64 + ch * 8);
      }
#pragma unroll
    for (int j = 0; j < 4; ++j)
#pragma unroll
      for (int kk = 0; kk < 2; ++kk) {
        int row = wc * 64 + j * 16 + l15;
        int ch = (kk * 4 + g) ^ (l15 & 7);
        bfv[j][kk] = *(const s16x8*)(lb + row * 64 + ch * 8);
      }
#pragma unroll
    for (int kk = 0; kk < 2; ++kk)
#pragma unroll
      for (int i = 0; i < MI; ++i)
#pragma unroll
        for (int j = 0; j < 4; ++j)
          acc[i][j] = mfma16(af[i][kk], bfv[j][kk], acc[i][j]);
    if (AF32 && more) stageA_write(buf ^ 1);  // HBM latency hidden under MFMA
    __syncthreads();
    buf ^= 1;
  }

#pragma unroll
  for (int j = 0; j < 4; ++j) {
    int col = bn * 128 + wc * 64 + j * 16 + l15;
    float bv = bias[col];
    int which = 0, rem = 0, h = 0, d = 0;
    if (MODE == 2) {
      which = col / 384;
      rem = col - which * 384;
      h = rem >> 5; d = rem & 31;
    }
#pragma unroll
    for (int i = 0; i < MI; ++i) {
      int row0 = bm * BM + wr * WM + i * 16 + g * 4;
      if (MODE == 2 && which == 2) {
        // V: write vt[bhs][d][key] directly; 4 consecutive keys = one s16x4
        int b = row0 >> 12, s = (row0 >> 10) & 3, key = row0 & 1023;
        s16x4 o;
#pragma unroll
        for (int r = 0; r < 4; ++r) o[r] = f2bf(acc[i][j][r] + bv);
        *(s16x4*)(vt + ((size_t)((b * 12 + h) * 4 + s) << 15) + d * 1024 + key) = o;
        continue;
      }
#pragma unroll
      for (int r = 0; r < 4; ++r) {
        int row = row0 + r;
        float v = acc[i][j][r] + bv;
        if (MODE == 1) {
          ((float*)out)[(size_t)row * N + col] = v;
        } else if (MODE == 0) {
          ((short*)out)[(size_t)row * N + col] = f2bf(v);
        } else {
          // fold hd^-0.5 * log2(e) into q so attn scores are in log2 units
          if (which == 0) v *= (0.17677669529663687f * 1.4426950408889634f);
          short bf = f2bf(v);
          int b = row >> 12, s = (row >> 10) & 3, key = row & 1023;
          size_t dst = ((size_t)((b * 12 + h) * 4 + s) << 15) + key * 32 + d;
          if (which) k_p[dst] = bf; else q_p[dst] = bf;
        }
      }
    }
  }
}

// ---------------- flash attention: 32x32 MFMA, fully in-register P ----------------
// S^T = mfma32(K, Q): col = query = l&31, row = key = (reg&3)+8*(reg>>2)+4*hh.
// P^T PV B-operand assembled in-register via cross-half exchange:
//   per 32-key block, u[j] = cvt2bf(p[2j],p[2j+1]) (keys {0,1}.. per reg pairs);
//   chunk0 (k=0..15): low frag [u0,u1,y0,y1], high [y0,y1,u2,u3],
//   y_i = shfl_xor(hh ? u_i : u_{i+2}, 32)  (one shfl serves both directions);
//   chunk1 same with u4..u7. NO LDS, NO fences, NO barriers.
// O^T = mfma32(V^T, P^T): col = query, row = d. lsum: 1 shfl at end.
// Q pre-scaled by hd^-0.5*log2e (r14): p = exp2(sa) directly.
__global__ __launch_bounds__(128, 2) void attn_kernel(
    const short* __restrict__ qp, const short* __restrict__ kp,
    const short* __restrict__ vt, short* __restrict__ ob) {
  int tid = threadIdx.x;
  int lane = tid & 63, w = tid >> 6;           // w in {0,1}
  int l31 = lane & 31, hh = lane >> 5;
  int bid = blockIdx.x;
  int bhs = bid % 192, qt = bid / 192;         // qt in 0..15, 64 q-rows each
  int s = bhs & 3, h = (bhs >> 2) % 12, b = bhs / 48;

  int q0 = qt * 64 + w * 32;
  const short* qb = qp + ((size_t)bhs << 15) + q0 * 32;
  const short* kb = kp + ((size_t)bhs << 15);
  const short* vb = vt + ((size_t)bhs << 15);

  // Q B-fragments: lane holds Q[query=l31][k = kh*16 + hh*8 + j]
  s16x8 qf[2];
  qf[0] = *(const s16x8*)(qb + l31 * 32 + hh * 8);
  qf[1] = *(const s16x8*)(qb + l31 * 32 + 16 + hh * 8);

  f32x16 oacc;
#pragma unroll
  for (int r = 0; r < 16; ++r) oacc[r] = 0.f;
  float lsum = 0.f;

  for (int t = 0; t < 8; ++t) {
#pragma unroll
    for (int kb32 = 0; kb32 < 4; ++kb32) {
      int keybase = t * 128 + kb32 * 32;
      // K A-fragments: lane holds K[key = keybase + l31][k = kh*16 + hh*8 + j]
      const short* kaddr = kb + (size_t)(keybase + l31) * 32 + hh * 8;
      s16x8 kf0 = *(const s16x8*)(kaddr);
      s16x8 kf1 = *(const s16x8*)(kaddr + 16);
      f32x16 sa;
#pragma unroll
      for (int r = 0; r < 16; ++r) sa[r] = 0.f;
      sa = mfma32(kf0, qf[0], sa);
      sa = mfma32(kf1, qf[1], sa);
      // softmax numerators (q pre-scaled; shift cancels in ratio)
      float p[16];
      float ps = 0.f;
#pragma unroll
      for (int r = 0; r < 16; ++r) {
        p[r] = __builtin_amdgcn_exp2f(sa[r]);
        ps += p[r];
      }
      lsum += ps;
      unsigned u[8];
#pragma unroll
      for (int j = 0; j < 8; ++j) u[j] = cvt2bf(p[2 * j], p[2 * j + 1]);
      // cross-half exchange for PV B-operand (P^T)
      unsigned y0 = __shfl_xor(hh ? u[0] : u[2], 32);
      unsigned y1 = __shfl_xor(hh ? u[1] : u[3], 32);
      unsigned y2 = __shfl_xor(hh ? u[4] : u[6], 32);
      unsigned y3 = __shfl_xor(hh ? u[5] : u[7], 32);
      u32x4 f0 = { hh ? y0 : u[0], hh ? y1 : u[1], hh ? u[2] : y0, hh ? u[3] : y1 };
      u32x4 f1 = { hh ? y2 : u[4], hh ? y3 : u[5], hh ? u[6] : y2, hh ? u[7] : y3 };
      // V A-fragments: lane holds V^T[d=l31][key = keybase + c*16 + hh*8 + j]
      const short* vaddr = vb + (size_t)l31 * 1024 + keybase + hh * 8;
      s16x8 vf0 = *(const s16x8*)(vaddr);
      s16x8 vf1 = *(const s16x8*)(vaddr + 16);
      oacc = mfma32(vf0, __builtin_bit_cast(s16x8, f0), oacc);
      oacc = mfma32(vf1, __builtin_bit_cast(s16x8, f1), oacc);
    }
  }
  // denominator: this lane covers 16 of 32 keys per block; other half has the rest
  lsum += __shfl_xor(lsum, 32);
  float inv = 1.0f / lsum;
  int tok = b * 4096 + s * 1024 + q0 + l31;
  short* obase = ob + (size_t)tok * 384 + h * 32;
#pragma unroll
  for (int rg = 0; rg < 4; ++rg) {
    int d = 8 * rg + 4 * hh;                   // rows (reg&3)+8*(reg>>2)+4*hh
    uint2 uo;
    uo.x = cvt2bf(oacc[rg * 4 + 0] * inv, oacc[rg * 4 + 1] * inv);
    uo.y = cvt2bf(oacc[rg * 4 + 2] * inv, oacc[rg * 4 + 3] * inv);
    *(s16x4*)(obase + d) = __builtin_bit_cast(s16x4, uo);
  }
}

// ---------------- launch ----------------
extern "C" void kernel_launch(void* const* d_in, const int* in_sizes, int n_in,
                              void* d_out, int out_size, void* d_ws, size_t ws_size,
                              hipStream_t stream) {
  const float* x        = (const float*)d_in[0];   // [4,4096,768]
  const float* W_reduce = (const float*)d_in[1];   // [768,384]
  const float* b_reduce = (const float*)d_in[2];   // [384]
  const float* W_qkv    = (const float*)d_in[3];   // [384,1152]
  const float* b_qkv    = (const float*)d_in[4];   // [1152]
  const float* W_proj   = (const float*)d_in[5];   // [384,768]
  const float* b_proj   = (const float*)d_in[6];   // [768]
  float* out = (float*)d_out;                      // [16384,768]

  char* ws = (char*)d_ws;
  short* wr_t    = (short*)(ws + 0);               // [384][768]    589824 B
  short* wqkv_t  = (short*)(ws + 589824);          // [1152][384]   884736 B
  short* wproj_t = (short*)(ws + 1474560);         // [768][384]    589824 B
  short* xr_b    = (short*)(ws + 2064384);         // [16384][384]  12582912 B
  short* o_b     = xr_b;                           // reuse after qkv GEMM
  short* q_p     = (short*)(ws + 14647296);        // [192][1024][32] 12582912 B
  short* k_p     = (short*)(ws + 27230208);        // 12582912 B
  short* vt      = (short*)(ws + 39813120);        // [192][32][1024] 12582912 B

  // all three weight transposes in one dispatch
  transpose_cast_all<<<1008, 256, 0, stream>>>(W_reduce, wr_t, W_qkv, wqkv_t, W_proj, wproj_t);

  // xr = x @ W_reduce + b_reduce  (f32 A fused-cast, bf16 out) — BM=64: 768 blocks
  gemm_bf16<0, true, 64><<<768, 256, 0, stream>>>(nullptr, x, wr_t, b_reduce, xr_b,
                                                  nullptr, nullptr, nullptr, 16384, 384, 768);
  // qkv = xr @ W_qkv + b_qkv  -> scatter q_p / k_p / vt-direct — BM=64: 2304 blocks
  gemm_bf16<2, false, 64><<<2304, 256, 0, stream>>>(xr_b, nullptr, wqkv_t, b_qkv, nullptr,
                                                    q_p, k_p, vt, 16384, 1152, 384);
  // attention -> o_b  (2-wave blocks, zero LDS, in-register P)
  attn_kernel<<<3072, 128, 0, stream>>>(q_p, k_p, vt, o_b);
  // out = o @ W_proj + b_proj (f32 out) — BM=64: 1536 blocks
  gemm_bf16<1, false, 64><<<1536, 256, 0, stream>>>(o_b, nullptr, wproj_t, b_proj, (void*)out,
                                                    nullptr, nullptr, nullptr, 16384, 768, 384);
}

// Round 20
// 138.181 us; speedup vs baseline: 1.0480x; 1.0480x over previous
//
#include <hip/hip_runtime.h>
#include <hip/hip_bf16.h>

typedef __attribute__((ext_vector_type(8))) short   s16x8;
typedef __attribute__((ext_vector_type(4))) short   s16x4;
typedef __attribute__((ext_vector_type(8))) __bf16  bf16x8;
typedef __attribute__((ext_vector_type(4))) float   f32x4;

__device__ __forceinline__ short f2bf(float f) {
  unsigned u = __builtin_bit_cast(unsigned, f);
  u += 0x7fffu + ((u >> 16) & 1u);          // round-to-nearest-even
  return (short)(u >> 16);
}

// two f32 -> packed bf16 pair via hardware packed cvt (m240). memcpy because
// __hip_bfloat162 is not trivially copyable (bit_cast rejected, r13).
__device__ __forceinline__ unsigned cvt2bf(float a, float b) {
  __hip_bfloat162 r = __float22bfloat162_rn(make_float2(a, b));
  unsigned u;
  __builtin_memcpy(&u, &r, 4);
  return u;
}

__device__ __forceinline__ f32x4 mfma16(s16x8 a, s16x8 b, f32x4 c) {
  return __builtin_amdgcn_mfma_f32_16x16x32_bf16(
      __builtin_bit_cast(bf16x8, a), __builtin_bit_cast(bf16x8, b), c, 0, 0, 0);
}

__device__ __forceinline__ void glds16(const short* g, short* l) {
  __builtin_amdgcn_global_load_lds(
      (__attribute__((address_space(1))) const void*)g,
      (__attribute__((address_space(3))) void*)l, 16, 0, 0);
}

// ---------------- merged transpose + cast of the 3 weights ----------------
__global__ __launch_bounds__(256) void transpose_cast_all(
    const float* __restrict__ s0, short* __restrict__ d0,
    const float* __restrict__ s1, short* __restrict__ d1,
    const float* __restrict__ s2, short* __restrict__ d2) {
  __shared__ float t[32 * 33];
  int id = blockIdx.x;
  const float* src; short* dst; int R, C, bx, by;
  if (id < 288)      { src = s0; dst = d0; R = 768; C = 384;  bx = id % 12;           by = id / 12; }
  else if (id < 720) { int l = id - 288; src = s1; dst = d1; R = 384; C = 1152; bx = l % 36; by = l / 36; }
  else               { int l = id - 720; src = s2; dst = d2; R = 384; C = 768;  bx = l % 24; by = l / 24; }
  int tid = threadIdx.x;
  int c0 = bx * 32, r0 = by * 32;
  for (int rep = 0; rep < 4; ++rep) {
    int idx = rep * 256 + tid;
    int rr = idx >> 5, cc = idx & 31;
    t[rr * 33 + cc] = src[(size_t)(r0 + rr) * C + c0 + cc];
  }
  __syncthreads();
  for (int rep = 0; rep < 4; ++rep) {
    int idx = rep * 256 + tid;
    int cc = idx >> 5, rr = idx & 31;
    dst[(size_t)(c0 + cc) * R + r0 + rr] = f2bf(t[rr * 33 + cc]);
  }
}

// ---------------- m97-style bf16 GEMM, templated block-M ----------------
// MODE 0: bf16 out. MODE 1: f32 out. MODE 2: qkv scatter (q pre-scaled),
//   V written DIRECTLY to vt[bhs][d][1024] (transposed) as s16x4 quads.
// AF32: A is f32; reg-stage (issue early, convert+ds_write after MFMA).
// BM=64 everywhere: finer grid granularity (tail-round idle shrinks).
template <int MODE, bool AF32, int BM>
__global__ __launch_bounds__(256, 2) void gemm_bf16(
    const short* __restrict__ A, const float* __restrict__ Af,
    const short* __restrict__ Bt,
    const float* __restrict__ bias, void* __restrict__ out,
    short* __restrict__ q_p, short* __restrict__ k_p, short* __restrict__ vt,
    int M, int N, int K) {
  constexpr int WM  = BM / 2;    // wave M-extent
  constexpr int MI  = WM / 16;   // M fragments per wave
  constexpr int AIT = BM / 32;   // A-stage iterations (256 thr x 16B)
  __shared__ short lds[2][(BM + 128) * 64];
  int tid = threadIdx.x;
  int lane = tid & 63, wid = tid >> 6;
  int l15 = lane & 15, g = lane >> 4;
  int nbn = N >> 7;
  int nwg = gridDim.x;
  int bid = blockIdx.x;
  int chunk = nwg >> 3;                       // all grids are %8 == 0
  int swz_bid = (bid & 7) * chunk + (bid >> 3);
  int bm = swz_bid / nbn, bn = swz_bid % nbn;
  int wr = wid >> 1, wc = wid & 1;

  const short* Ab = AF32 ? nullptr : (A + (size_t)(bm * BM) * K);
  const float* Afb = AF32 ? (Af + (size_t)(bm * BM) * K) : nullptr;
  const short* Bb = Bt + (size_t)(bn * 128) * K;

  f32x4 acc[MI][4];
#pragma unroll
  for (int i = 0; i < MI; ++i)
#pragma unroll
    for (int j = 0; j < 4; ++j) acc[i][j] = (f32x4){0.f, 0.f, 0.f, 0.f};

  f32x4 areg[AIT][2];                         // AF32: 8 floats per c-slot
  int nk = K >> 6;

  auto stageB = [&](int bufi, int kt) {
    const short* gb = Bb + kt * 64;
#pragma unroll
    for (int it = 0; it < 4; ++it) {
      int c = it * 256 + tid;
      int row = c >> 3, pc = c & 7;
      int lc = pc ^ (row & 7);                // pre-swizzled source (rule #21)
      glds16(gb + (size_t)row * K + lc * 8,
             &lds[bufi][BM * 64 + (it * 256 + wid * 64) * 8]);
    }
  };
  auto stageA_lds = [&](int bufi, int kt) {
    const short* ga = Ab + kt * 64;
#pragma unroll
    for (int it = 0; it < AIT; ++it) {
      int c = it * 256 + tid;
      int row = c >> 3, pc = c & 7;
      int lc = pc ^ (row & 7);
      glds16(ga + (size_t)row * K + lc * 8,
             &lds[bufi][(it * 256 + wid * 64) * 8]);
    }
  };
  auto stageA_issue = [&](int kt) {           // f32 global -> regs (no wait yet)
#pragma unroll
    for (int it = 0; it < AIT; ++it) {
      int c = it * 256 + tid;
      int row = c >> 3, pc = c & 7;
      int lc = pc ^ (row & 7);
      const float* src = Afb + (size_t)row * K + kt * 64 + lc * 8;
      areg[it][0] = *(const f32x4*)(src);
      areg[it][1] = *(const f32x4*)(src + 4);
    }
  };
  auto stageA_write = [&](int bufi) {         // regs -> bf16 -> LDS (same image)
#pragma unroll
    for (int it = 0; it < AIT; ++it) {
      int c = it * 256 + tid;
      s16x8 o;
#pragma unroll
      for (int q = 0; q < 4; ++q) {
        o[q]     = f2bf(areg[it][0][q]);
        o[q + 4] = f2bf(areg[it][1][q]);
      }
      *(s16x8*)(&lds[bufi][0] + (size_t)c * 8) = o;
    }
  };

  if (AF32) { stageA_issue(0); stageB(0, 0); stageA_write(0); }
  else      { stageA_lds(0, 0); stageB(0, 0); }
  __syncthreads();
  int buf = 0;
  for (int kt = 0; kt < nk; ++kt) {
    bool more = (kt + 1 < nk);
    if (more) {
      if (AF32) stageA_issue(kt + 1); else stageA_lds(buf ^ 1, kt + 1);
      stageB(buf ^ 1, kt + 1);
    }
    const short* la = &lds[buf][0];
    const short* lb = &lds[buf][BM * 64];
    s16x8 af[MI][2], bfv[4][2];
#pragma unroll
    for (int i = 0; i < MI; ++i)
#pragma unroll
      for (int kk = 0; kk < 2; ++kk) {
        int row = wr * WM + i * 16 + l15;
        int ch = (kk * 4 + g) ^ (l15 & 7);
        af[i][kk] = *(const s16x8*)(la + row * 64 + ch * 8);
      }
#pragma unroll
    for (int j = 0; j < 4; ++j)
#pragma unroll
      for (int kk = 0; kk < 2; ++kk) {
        int row = wc * 64 + j * 16 + l15;
        int ch = (kk * 4 + g) ^ (l15 & 7);
        bfv[j][kk] = *(const s16x8*)(lb + row * 64 + ch * 8);
      }
#pragma unroll
    for (int kk = 0; kk < 2; ++kk)
#pragma unroll
      for (int i = 0; i < MI; ++i)
#pragma unroll
        for (int j = 0; j < 4; ++j)
          acc[i][j] = mfma16(af[i][kk], bfv[j][kk], acc[i][j]);
    if (AF32 && more) stageA_write(buf ^ 1);  // HBM latency hidden under MFMA
    __syncthreads();
    buf ^= 1;
  }

#pragma unroll
  for (int j = 0; j < 4; ++j) {
    int col = bn * 128 + wc * 64 + j * 16 + l15;
    float bv = bias[col];
    int which = 0, rem = 0, h = 0, d = 0;
    if (MODE == 2) {
      which = col / 384;
      rem = col - which * 384;
      h = rem >> 5; d = rem & 31;
    }
#pragma unroll
    for (int i = 0; i < MI; ++i) {
      int row0 = bm * BM + wr * WM + i * 16 + g * 4;
      if (MODE == 2 && which == 2) {
        // V: write vt[bhs][d][key] directly; 4 consecutive keys = one s16x4
        int b = row0 >> 12, s = (row0 >> 10) & 3, key = row0 & 1023;
        s16x4 o;
#pragma unroll
        for (int r = 0; r < 4; ++r) o[r] = f2bf(acc[i][j][r] + bv);
        *(s16x4*)(vt + ((size_t)((b * 12 + h) * 4 + s) << 15) + d * 1024 + key) = o;
        continue;
      }
#pragma unroll
      for (int r = 0; r < 4; ++r) {
        int row = row0 + r;
        float v = acc[i][j][r] + bv;
        if (MODE == 1) {
          ((float*)out)[(size_t)row * N + col] = v;
        } else if (MODE == 0) {
          ((short*)out)[(size_t)row * N + col] = f2bf(v);
        } else {
          // fold hd^-0.5 * log2(e) into q so attn scores are in log2 units
          if (which == 0) v *= (0.17677669529663687f * 1.4426950408889634f);
          short bf = f2bf(v);
          int b = row >> 12, s = (row >> 10) & 3, key = row & 1023;
          size_t dst = ((size_t)((b * 12 + h) * 4 + s) << 15) + key * 32 + d;
          if (which) k_p[dst] = bf; else q_p[dst] = bf;
        }
      }
    }
  }
}

// ---------------- flash attention: swapped QK^T, 2-wave blocks (r18 = BEST) ----
// REVERT of r19's 32x32 in-register experiment (87.4 us, numerically correct
// but slower: one serial oacc chain lost the ILP of sa[2][8]'s 16 independent
// accumulators). r18 body: 16x16 MFMA, LDS P round-trip, no setprio — 80.1 us.
// Attn plateau is the per-wave dependent chain at ~2.6 waves/SIMD; LDS-removal,
// fence masks, occupancy moves, VALU diet all measured null or negative.
__global__ __launch_bounds__(128, 2) void attn_kernel(
    const short* __restrict__ qp, const short* __restrict__ kp,
    const short* __restrict__ vt, short* __restrict__ ob) {
  __shared__ short plds[2][32 * 136];          // per-wave P[32][272B]
  int tid = threadIdx.x;
  int lane = tid & 63, w = tid >> 6;           // w in {0,1}
  int l15 = lane & 15, g = lane >> 4;
  int bid = blockIdx.x;
  int bhs = bid % 192, qt = bid / 192;         // qt in 0..15, 64 q-rows each
  int s = bhs & 3, h = (bhs >> 2) % 12, b = bhs / 48;

  const short* qb = qp + ((size_t)bhs << 15) + (qt * 64 + w * 32) * 32;
  const short* kb = kp + ((size_t)bhs << 15);
  const short* vb = vt + ((size_t)bhs << 15);

  s16x8 qf[2];
#pragma unroll
  for (int i = 0; i < 2; ++i)
    qf[i] = *(const s16x8*)(qb + (i * 16 + l15) * 32 + g * 8);

  f32x4 oacc[2][2];
#pragma unroll
  for (int i = 0; i < 2; ++i)
#pragma unroll
    for (int n = 0; n < 2; ++n) oacc[i][n] = (f32x4){0.f, 0.f, 0.f, 0.f};
  float lsum[2] = {0.f, 0.f};

  char* pw = (char*)&plds[w][0];
  int swz = (l15 >> 3) << 4;                   // 1-bit XOR (row-pure, bijective)

  for (int t = 0; t < 8; ++t) {
    f32x4 sa[2][8];
#pragma unroll
    for (int i = 0; i < 2; ++i)
#pragma unroll
      for (int kn = 0; kn < 8; ++kn) sa[i][kn] = (f32x4){0.f, 0.f, 0.f, 0.f};
#pragma unroll
    for (int kn = 0; kn < 8; ++kn) {
      s16x8 kf = *(const s16x8*)(kb + (size_t)(t * 128 + kn * 16 + l15) * 32 + g * 8);
      sa[0][kn] = mfma16(kf, qf[0], sa[0][kn]);
      sa[1][kn] = mfma16(kf, qf[1], sa[1][kn]);
    }
    // numerators: p = exp2(sa) directly (q pre-scaled; shift cancels in ratio)
#pragma unroll
    for (int i = 0; i < 2; ++i) {
      float ps = 0.f;
#pragma unroll
      for (int kn = 0; kn < 8; ++kn) {
        float p0 = __builtin_amdgcn_exp2f(sa[i][kn][0]);
        float p1 = __builtin_amdgcn_exp2f(sa[i][kn][1]);
        float p2 = __builtin_amdgcn_exp2f(sa[i][kn][2]);
        float p3 = __builtin_amdgcn_exp2f(sa[i][kn][3]);
        ps += (p0 + p1) + (p2 + p3);
        uint2 u;
        u.x = cvt2bf(p0, p1);
        u.y = cvt2bf(p2, p3);
        *(s16x4*)(pw + (i * 16 + l15) * 272 + ((kn * 32 + g * 8) ^ swz)) =
            __builtin_bit_cast(s16x4, u);
      }
      lsum[i] += ps;                           // per-lane partial; reduced at end
    }
    // DS-only fence: P-stores stay before PV P-loads; VALU/VMEM/MFMA may cross
    __builtin_amdgcn_sched_barrier(0x7F);
#pragma unroll
    for (int kk = 0; kk < 4; ++kk) {
      s16x8 pa[2];
#pragma unroll
      for (int i = 0; i < 2; ++i)
        pa[i] = *(const s16x8*)(pw + (i * 16 + l15) * 272 + ((kk * 64 + g * 16) ^ swz));
#pragma unroll
      for (int n = 0; n < 2; ++n) {
        s16x8 vf = *(const s16x8*)(vb + (size_t)(n * 16 + l15) * 1024 + t * 128 + kk * 32 + g * 8);
        oacc[0][n] = mfma16(vf, pa[0], oacc[0][n]);
        oacc[1][n] = mfma16(vf, pa[1], oacc[1][n]);
      }
    }
    // DS-only fence: next tile's P-stores stay after this tile's P-loads
    __builtin_amdgcn_sched_barrier(0x7F);
  }
  // final denominator: sum across the 4 g-groups (keys partition over g)
#pragma unroll
  for (int i = 0; i < 2; ++i) {
    float v = lsum[i];
    v += __shfl_xor(v, 16);
    v += __shfl_xor(v, 32);
    lsum[i] = v;
  }
  int tokq0 = b * 4096 + s * 1024 + qt * 64 + w * 32;
#pragma unroll
  for (int i = 0; i < 2; ++i) {
    float inv = 1.0f / lsum[i];
    int tok = tokq0 + i * 16 + l15;
#pragma unroll
    for (int n = 0; n < 2; ++n) {
      uint2 u;
      u.x = cvt2bf(oacc[i][n][0] * inv, oacc[i][n][1] * inv);
      u.y = cvt2bf(oacc[i][n][2] * inv, oacc[i][n][3] * inv);
      *(s16x4*)(ob + (size_t)tok * 384 + h * 32 + n * 16 + g * 4) =
          __builtin_bit_cast(s16x4, u);
    }
  }
}

// ---------------- launch ----------------
extern "C" void kernel_launch(void* const* d_in, const int* in_sizes, int n_in,
                              void* d_out, int out_size, void* d_ws, size_t ws_size,
                              hipStream_t stream) {
  const float* x        = (const float*)d_in[0];   // [4,4096,768]
  const float* W_reduce = (const float*)d_in[1];   // [768,384]
  const float* b_reduce = (const float*)d_in[2];   // [384]
  const float* W_qkv    = (const float*)d_in[3];   // [384,1152]
  const float* b_qkv    = (const float*)d_in[4];   // [1152]
  const float* W_proj   = (const float*)d_in[5];   // [384,768]
  const float* b_proj   = (const float*)d_in[6];   // [768]
  float* out = (float*)d_out;                      // [16384,768]

  char* ws = (char*)d_ws;
  short* wr_t    = (short*)(ws + 0);               // [384][768]    589824 B
  short* wqkv_t  = (short*)(ws + 589824);          // [1152][384]   884736 B
  short* wproj_t = (short*)(ws + 1474560);         // [768][384]    589824 B
  short* xr_b    = (short*)(ws + 2064384);         // [16384][384]  12582912 B
  short* o_b     = xr_b;                           // reuse after qkv GEMM
  short* q_p     = (short*)(ws + 14647296);        // [192][1024][32] 12582912 B
  short* k_p     = (short*)(ws + 27230208);        // 12582912 B
  short* vt      = (short*)(ws + 39813120);        // [192][32][1024] 12582912 B

  // all three weight transposes in one dispatch
  transpose_cast_all<<<1008, 256, 0, stream>>>(W_reduce, wr_t, W_qkv, wqkv_t, W_proj, wproj_t);

  // xr = x @ W_reduce + b_reduce  (f32 A fused-cast, bf16 out) — BM=64: 768 blocks
  gemm_bf16<0, true, 64><<<768, 256, 0, stream>>>(nullptr, x, wr_t, b_reduce, xr_b,
                                                  nullptr, nullptr, nullptr, 16384, 384, 768);
  // qkv = xr @ W_qkv + b_qkv  -> scatter q_p / k_p / vt-direct — BM=64: 2304 blocks
  gemm_bf16<2, false, 64><<<2304, 256, 0, stream>>>(xr_b, nullptr, wqkv_t, b_qkv, nullptr,
                                                    q_p, k_p, vt, 16384, 1152, 384);
  // attention -> o_b  (2-wave blocks, 16 q-tiles per bhs)
  attn_kernel<<<3072, 128, 0, stream>>>(q_p, k_p, vt, o_b);
  // out = o @ W_proj + b_proj (f32 out) — BM=64: 1536 blocks
  gemm_bf16<1, false, 64><<<1536, 256, 0, stream>>>(o_b, nullptr, wproj_t, b_proj, (void*)out,
                                                    nullptr, nullptr, nullptr, 16384, 768, 384);
}